// Round 11
// baseline (171.174 us; speedup 1.0000x reference)
//
#include <hip/hip_runtime.h>
#include <hip/hip_bf16.h>
#include <float.h>

#define NN 2048
#define HH 16
#define DDIM 64
#define QB 128  // q-rows per block = 8 waves x 16 rows
#define KB 64
#define KPITCH 144            // LDS row pitch in bytes
#define PARTF 8448            // floats per partial: 128x64 O + 128 m + 128 l
#define NSLOT 8               // max kv-chunk partials per q-tile (32 tiles / 4)
#define NCHUNK 1152           // 16 heads * 72 chunks
#define WS_PART_OFF 2048      // floats: [0]=counter, [512..1536) vmean
#define WS_NEED ((WS_PART_OFF + 16ull * HH * NSLOT * PARTF) * 4ull)

typedef __bf16 bf16x8 __attribute__((ext_vector_type(8)));
typedef __bf16 bf16x4 __attribute__((ext_vector_type(4)));
typedef __bf16 bf16x2 __attribute__((ext_vector_type(2)));
typedef float f32x4 __attribute__((ext_vector_type(4)));

// Raw barrier: LDS-writes visible; outstanding GLOBAL prefetch loads stay in flight.
__device__ __forceinline__ void barw() {
  __builtin_amdgcn_sched_barrier(0);
  asm volatile("s_waitcnt lgkmcnt(0)" ::: "memory");
  __builtin_amdgcn_s_barrier();
  __builtin_amdgcn_sched_barrier(0);
}

__device__ __forceinline__ unsigned pack2(float a, float b) {
  union { __bf16 h[2]; unsigned u; } x;
  x.h[0] = (__bf16)a; x.h[1] = (__bf16)b;
  return x.u;
}

// ============================================================================
// vmean: per-head V column means (for fully-masked rows). 16 blocks, coalesced.
// ============================================================================
__global__ __launch_bounds__(256) void vmean_kernel(
    const float* __restrict__ vg, float* __restrict__ wsv)
{
  __shared__ float red[4][DDIM];
  const int h = blockIdx.x;
  const int t = threadIdx.x;
  const int d = t & 63;
  const int part = t >> 6;        // 0..3, each covers 512 rows
  float s = 0.f;
  const float* vp = vg + ((size_t)(h * NN) + part * 512) * DDIM + d;
  for (int j = 0; j < 512; ++j) s += vp[(size_t)j * DDIM];
  red[part][d] = s;
  __syncthreads();
  if (t < DDIM) {
    wsv[h * DDIM + t] =
      (red[0][t] + red[1][t] + red[2][t] + red[3][t]) * (1.0f / (float)NN);
  }
}

// ============================================================================
// R11 part: 512-thread / 8-wave blocks, QB=128. Doubles in-flight PB bytes
// per block (8 waves x 12 loads) against the latency-equilibrium bottleneck;
// K/V staged once per 128 q-rows (halves KV delivered bytes + barriers/unit).
// Work-stealing: 1152 chunks (<=4 kv-tiles), big-first; grid 512 = 2/CU.
// Chunk c: h=c&15, rank=c>>4. rank<64: full len-4 chunks walking qt=15 down
// (nf=(qt+1)>>1); rank>=64: idx=rank-64, qt=14-2*idx, ci=7-idx, len=2.
// ============================================================================
__global__ __launch_bounds__(512, 2) void attend_part(
    const float* __restrict__ qg, const float* __restrict__ kg,
    const float* __restrict__ vg, const unsigned int* __restrict__ maskw,
    const float* __restrict__ biasg, const float* __restrict__ prevg,
    float* __restrict__ opart, unsigned int* __restrict__ counter)
{
  __shared__ char ksh[KB * KPITCH]   __attribute__((aligned(16))); // [kv][d] bf16
  __shared__ char vsh[DDIM * KPITCH] __attribute__((aligned(16))); // [d][kv] bf16
  __shared__ int chunk_s;

  const int t    = threadIdx.x;
  const int lane = t & 63;
  const int w    = t >> 6;        // 0..7

  // --- mask element-width detection: 4-byte (int/float bool) vs 1-byte ---
  unsigned int mwrd = maskw[t & 255];
  const int mask4 = __syncthreads_and(mwrd == 0u || mwrd == 1u || mwrd == 0x3F800000u);

  const int llo = lane & 15;
  const int lhi = lane >> 4;
  const int cbi  = t & 15;        // staging col group: cb = cbi*4
  const int cb   = cbi << 2;
  const int rgrp = t >> 4;        // staging row group: rows rgrp*2, rgrp*2+1

  for (;;) {
    if (t == 0) chunk_s = (int)atomicAdd(counter, 1u);
    __syncthreads();
    const int c = chunk_s;
    if (c >= NCHUNK) break;
    const int h    = c & 15;
    const int rank = c >> 4;

    int qt, ci, len;
    if (rank < 64) {
      int kk = rank;
      qt = 15;
      for (;;) {
        const int nf = (qt + 1) >> 1;
        if (kk < nf) { ci = kk; len = 4; break; }
        kk -= nf; --qt;
      }
    } else {
      const int idx = rank - 64;
      qt  = 14 - (idx << 1);
      ci  = 7 - idx;
      len = 2;
    }
    const int lo = ci << 2;
    const int hi = lo + len;
    const int qrow0 = qt * QB;
    const int qrow_g = qrow0 + w * 16 + llo;   // this lane's q-row

    // --- Q fragments (B operand), scale 1/8 folded in ---
    bf16x8 aq[2];
    {
      const float* qp = qg + ((size_t)(h * NN + qrow_g)) * DDIM + lhi * 8;
#pragma unroll
      for (int ks = 0; ks < 2; ++ks) {
        float4 f0 = *(const float4*)(qp + ks * 32);
        float4 f1 = *(const float4*)(qp + ks * 32 + 4);
        bf16x8 a;
        a[0] = (__bf16)(f0.x * 0.125f); a[1] = (__bf16)(f0.y * 0.125f);
        a[2] = (__bf16)(f0.z * 0.125f); a[3] = (__bf16)(f0.w * 0.125f);
        a[4] = (__bf16)(f1.x * 0.125f); a[5] = (__bf16)(f1.y * 0.125f);
        a[6] = (__bf16)(f1.z * 0.125f); a[7] = (__bf16)(f1.w * 0.125f);
        aq[ks] = a;
      }
    }

    f32x4 oacc[4];   // O^T frags: oacc[df][r] = O[q=llo-row][d=df*16+lhi*4+r]
#pragma unroll
    for (int i = 0; i < 4; ++i) { f32x4 z = {0.f, 0.f, 0.f, 0.f}; oacc[i] = z; }
    float m_r = -FLT_MAX, l_r = 0.f;

    // ---- prefetch registers ----
    float4 kpre[2], vpre[2];
    float4 ppre[4], bpre[4];
    uint4  mpre[4];

    auto issueKV = [&](int kv0) {
#pragma unroll
      for (int e = 0; e < 2; ++e) {
        const int row = (rgrp << 1) + e;
        const size_t gofs = ((size_t)(h * NN + kv0 + row)) * DDIM + cb;
        kpre[e] = *(const float4*)(kg + gofs);
        vpre[e] = *(const float4*)(vg + gofs);
      }
    };
    auto issuePB = [&](int kv0) {
#pragma unroll
      for (int kf = 0; kf < 4; ++kf) {
        const int col = kv0 + kf * 16 + lhi * 4;
        const size_t base = ((size_t)(h * NN) + qrow_g) * NN + col;
        ppre[kf] = *(const float4*)(prevg + base);
        bpre[kf] = *(const float4*)(biasg + base);
        const size_t midx = (size_t)qrow_g * NN + col;
        if (mask4) {
          mpre[kf] = *(const uint4*)(maskw + midx);
        } else {
          mpre[kf].x = *(const unsigned int*)((const unsigned char*)maskw + midx);
        }
      }
    };

    issueKV(lo * KB);
    issuePB(lo * KB);

    for (int tt = lo; tt < hi; ++tt) {
      const int kv0 = tt * KB;
      // ---- phase 1: stage K [kv][d] and V^T [d][kv], f32->bf16, pitch-144 ----
#pragma unroll
      for (int e = 0; e < 2; ++e) {
        const int row = (rgrp << 1) + e;
        float4 kf = kpre[e];
        bf16x4 kb4;
        kb4[0] = (__bf16)kf.x; kb4[1] = (__bf16)kf.y;
        kb4[2] = (__bf16)kf.z; kb4[3] = (__bf16)kf.w;
        *(bf16x4*)(ksh + row * KPITCH + (cb << 1)) = kb4;
      }
#pragma unroll
      for (int j = 0; j < 4; ++j) {
        bf16x2 vb2;
        vb2[0] = (__bf16)vpre[0][j];
        vb2[1] = (__bf16)vpre[1][j];
        *(bf16x2*)(vsh + (cb + j) * KPITCH + (rgrp << 2)) = vb2;
      }
      // keep current tile's softmax operands
      float4 pc[4], bc[4]; uint4 mc[4];
#pragma unroll
      for (int kf = 0; kf < 4; ++kf) { pc[kf] = ppre[kf]; bc[kf] = bpre[kf]; mc[kf] = mpre[kf]; }
      // issue next tile's loads (fly across the raw barriers)
      if (tt + 1 < hi) { issueKV(kv0 + KB); issuePB(kv0 + KB); }
      barw();

      // ---- QK^T swapped: S^T[kv][q], each lane: q=llo-row, 16 kv values ----
      f32x4 s[4];
#pragma unroll
      for (int kf = 0; kf < 4; ++kf) { f32x4 z = {0.f, 0.f, 0.f, 0.f}; s[kf] = z; }
#pragma unroll
      for (int ks = 0; ks < 2; ++ks) {
#pragma unroll
        for (int kf = 0; kf < 4; ++kf) {
          const int kvr = kf * 16 + llo;
          bf16x8 ak = *(const bf16x8*)(ksh + kvr * KPITCH + ((ks * 32 + lhi * 8) << 1));
          s[kf] = __builtin_amdgcn_mfma_f32_16x16x32_bf16(ak, aq[ks], s[kf], 0, 0, 0);
        }
      }

      // ---- softmax, fully in-register (row = q = llo; 4 lanes/row via xor16/32) ----
      float p[4][4];
      float pmax = -FLT_MAX;
#pragma unroll
      for (int kf = 0; kf < 4; ++kf) {
        float pa[4] = {pc[kf].x, pc[kf].y, pc[kf].z, pc[kf].w};
        float ba[4] = {bc[kf].x, bc[kf].y, bc[kf].z, bc[kf].w};
        unsigned mb[4];
        if (mask4) { mb[0] = mc[kf].x; mb[1] = mc[kf].y; mb[2] = mc[kf].z; mb[3] = mc[kf].w; }
        else {
          mb[0] = mc[kf].x & 0xffu; mb[1] = (mc[kf].x >> 8) & 0xffu;
          mb[2] = (mc[kf].x >> 16) & 0xffu; mb[3] = mc[kf].x >> 24;
        }
#pragma unroll
        for (int r = 0; r < 4; ++r) {
          const int j = kv0 + kf * 16 + lhi * 4 + r;
          float sv = s[kf][r] + pa[r] + ba[r];
          if (j > qrow_g || mb[r] == 0u) sv = -FLT_MAX;
          p[kf][r] = sv;
          pmax = fmaxf(pmax, sv);
        }
      }
      pmax = fmaxf(pmax, __shfl_xor(pmax, 16));
      pmax = fmaxf(pmax, __shfl_xor(pmax, 32));
      const float mnew = fmaxf(m_r, pmax);
      const float resc = __expf(m_r - mnew);   // exp(0)=1 when both -FLT_MAX (finite)
      float psum = 0.f;
#pragma unroll
      for (int kf = 0; kf < 4; ++kf)
#pragma unroll
        for (int r = 0; r < 4; ++r) {
          float e = __expf(p[kf][r] - mnew);
          p[kf][r] = e;
          psum += e;
        }
      psum += __shfl_xor(psum, 16);
      psum += __shfl_xor(psum, 32);
      l_r = l_r * resc + psum;
      m_r = mnew;
#pragma unroll
      for (int df = 0; df < 4; ++df) {
        oacc[df][0] *= resc; oacc[df][1] *= resc;
        oacc[df][2] *= resc; oacc[df][3] *= resc;
      }

      // ---- pack P -> bf16 pairs; redistribute P^T into PV B-operand; PV MFMAs ----
      unsigned U[4][2];
#pragma unroll
      for (int kf = 0; kf < 4; ++kf) {
        U[kf][0] = pack2(p[kf][0], p[kf][1]);
        U[kf][1] = pack2(p[kf][2], p[kf][3]);
      }
#pragma unroll
      for (int ks = 0; ks < 2; ++ks) {
        unsigned bb[4];
#pragma unroll
        for (int m = 0; m < 4; ++m) {
          const int src = llo + ((((lhi & 1) << 1) + (m >> 1)) << 4);
          const int va = __shfl((int)U[2 * ks + 0][m & 1], src);
          const int vb = __shfl((int)U[2 * ks + 1][m & 1], src);
          bb[m] = (lhi >> 1) ? (unsigned)vb : (unsigned)va;
        }
        union { unsigned u[4]; bf16x8 v; } pb_;
        pb_.u[0] = bb[0]; pb_.u[1] = bb[1]; pb_.u[2] = bb[2]; pb_.u[3] = bb[3];
#pragma unroll
        for (int df = 0; df < 4; ++df) {
          const int dr = df * 16 + llo;
          bf16x8 vf = *(const bf16x8*)(vsh + dr * KPITCH + ((ks * 32 + lhi * 8) << 1));
          oacc[df] = __builtin_amdgcn_mfma_f32_16x16x32_bf16(vf, pb_.v, oacc[df], 0, 0, 0);
        }
      }
      barw();   // all waves done reading ksh/vsh before next staging overwrite
    } // kv tiles

    // ---- write partial (unnormalized O, m, l) ----
    float* pb = opart + (size_t)(((h * 16 + qt) << 3) + ci) * PARTF;
    const int rowl = w * 16 + llo;   // 0..127
#pragma unroll
    for (int df = 0; df < 4; ++df) {
      *(f32x4*)(pb + rowl * 64 + df * 16 + lhi * 4) = oacc[df];
    }
    if (lhi == 0) {
      pb[8192 + rowl] = m_r;
      pb[8320 + rowl] = l_r;
    }
    __syncthreads();   // chunk done; safe to reuse chunk_s/LDS
  } // chunk loop
}

// ============================================================================
// combine: merge up to 8 kv-chunk partials per (qt,h); dead rows -> vmean.
// grid (16 qt, 16 h) x 256 threads; thread: row r=t>>1, cols (t&1)*32..+31.
// ============================================================================
__global__ __launch_bounds__(256) void attend_combine(
    const float* __restrict__ opart, const float* __restrict__ wsv,
    float* __restrict__ outg)
{
  const int qt  = blockIdx.x;
  const int h   = blockIdx.y;
  const int t   = threadIdx.x;
  const int nch = (2 * qt + 5) >> 2;   // ceil((2qt+2)/4)
  const float* base = opart + (size_t)((h * 16 + qt) << 3) * PARTF;
  const int r  = t >> 1;           // 0..127
  const int c0 = (t & 1) * 32;     // 0 or 32

  float m = -FLT_MAX;
  for (int ci = 0; ci < nch; ++ci)
    m = fmaxf(m, base[(size_t)ci * PARTF + 8192 + r]);
  const bool dead = (m == -FLT_MAX);

  float l = 0.f;
  f32x4 a0 = {0,0,0,0}, a1 = {0,0,0,0}, a2 = {0,0,0,0}, a3 = {0,0,0,0};
  f32x4 a4 = {0,0,0,0}, a5 = {0,0,0,0}, a6 = {0,0,0,0}, a7 = {0,0,0,0};
  for (int ci = 0; ci < nch; ++ci) {
    const float* pb = base + (size_t)ci * PARTF;
    const float wgt = dead ? 0.f : __expf(pb[8192 + r] - m);
    l += pb[8320 + r] * wgt;
    const float* rp = pb + r * 64 + c0;
    a0 += *(const f32x4*)(rp + 0)  * wgt;
    a1 += *(const f32x4*)(rp + 4)  * wgt;
    a2 += *(const f32x4*)(rp + 8)  * wgt;
    a3 += *(const f32x4*)(rp + 12) * wgt;
    a4 += *(const f32x4*)(rp + 16) * wgt;
    a5 += *(const f32x4*)(rp + 20) * wgt;
    a6 += *(const f32x4*)(rp + 24) * wgt;
    a7 += *(const f32x4*)(rp + 28) * wgt;
  }

  const float invl = dead ? 0.f : (1.0f / l);
  float* op = outg + ((size_t)(h * NN) + qt * QB + r) * DDIM + c0;
  const float* vm = wsv + h * DDIM + c0;
#pragma unroll
  for (int i = 0; i < 8; ++i) {
    const f32x4 ai = (i == 0) ? a0 : (i == 1) ? a1 : (i == 2) ? a2 : (i == 3) ? a3
                   : (i == 4) ? a4 : (i == 5) ? a5 : (i == 6) ? a6 : a7;
    float4 o;
    o.x = dead ? vm[i * 4 + 0] : ai[0] * invl;
    o.y = dead ? vm[i * 4 + 1] : ai[1] * invl;
    o.z = dead ? vm[i * 4 + 2] : ai[2] * invl;
    o.w = dead ? vm[i * 4 + 3] : ai[3] * invl;
    *(float4*)(op + i * 4) = o;
  }
}

// ============================================================================
// Fallback: single-kernel version (used only if ws_size is too small).
// ============================================================================
__global__ __launch_bounds__(256, 2) void attend_single(
    const float* __restrict__ qg, const float* __restrict__ kg,
    const float* __restrict__ vg, const unsigned int* __restrict__ maskw,
    const float* __restrict__ biasg, const float* __restrict__ prevg,
    float* __restrict__ outg)
{
  __shared__ char  ksh[KB * KPITCH]   __attribute__((aligned(16)));
  __shared__ char  vsh[DDIM * KPITCH] __attribute__((aligned(16)));
  __shared__ float vmean_s[DDIM];

  const int t    = threadIdx.x;
  const int lane = t & 63;
  const int w    = t >> 6;
  const int x    = blockIdx.x;
  const int h    = blockIdx.y;
  const int qt   = (h < 8) ? x : (31 - x);
  const int qrow0 = qt * 64;

  unsigned int mwrd = maskw[t & 255];
  const int mask4 = __syncthreads_and(mwrd == 0u || mwrd == 1u || mwrd == 0x3F800000u);

  const int llo = lane & 15;
  const int lhi = lane >> 4;
  const int cbi  = t & 15;
  const int cb   = cbi << 2;
  const int rgrp = t >> 4;
  const int qrow_g = qrow0 + w * 16 + llo;

  bf16x8 aq[2];
  {
    const float* qp = qg + ((size_t)(h * NN + qrow_g)) * DDIM + lhi * 8;
#pragma unroll
    for (int ks = 0; ks < 2; ++ks) {
      float4 f0 = *(const float4*)(qp + ks * 32);
      float4 f1 = *(const float4*)(qp + ks * 32 + 4);
      bf16x8 a;
      a[0] = (__bf16)(f0.x * 0.125f); a[1] = (__bf16)(f0.y * 0.125f);
      a[2] = (__bf16)(f0.z * 0.125f); a[3] = (__bf16)(f0.w * 0.125f);
      a[4] = (__bf16)(f1.x * 0.125f); a[5] = (__bf16)(f1.y * 0.125f);
      a[6] = (__bf16)(f1.z * 0.125f); a[7] = (__bf16)(f1.w * 0.125f);
      aq[ks] = a;
    }
  }

  f32x4 oacc[4];
#pragma unroll
  for (int i = 0; i < 4; ++i) { f32x4 z = {0.f, 0.f, 0.f, 0.f}; oacc[i] = z; }
  float m_r = -FLT_MAX, l_r = 0.f;

  float4 kpre[4], vpre[4];
  float4 ppre[4], bpre[4];
  uint4  mpre[4];

  auto issueKV = [&](int kv0) {
#pragma unroll
    for (int e = 0; e < 4; ++e) {
      const int row = (rgrp << 2) + e;
      const size_t gofs = ((size_t)(h * NN + kv0 + row)) * DDIM + cb;
      kpre[e] = *(const float4*)(kg + gofs);
      vpre[e] = *(const float4*)(vg + gofs);
    }
  };
  auto issuePB = [&](int kv0) {
#pragma unroll
    for (int kf = 0; kf < 4; ++kf) {
      const int col = kv0 + kf * 16 + lhi * 4;
      const size_t base = ((size_t)(h * NN) + qrow_g) * NN + col;
      ppre[kf] = *(const float4*)(prevg + base);
      bpre[kf] = *(const float4*)(biasg + base);
      const size_t midx = (size_t)qrow_g * NN + col;
      if (mask4) mpre[kf] = *(const uint4*)(maskw + midx);
      else       mpre[kf].x = *(const unsigned int*)((const unsigned char*)maskw + midx);
    }
  };

  const int Tq = qt + 1;
  issueKV(0);
  issuePB(0);

  for (int tt = 0; tt < Tq; ++tt) {
    const int kv0 = tt * KB;
#pragma unroll
    for (int e = 0; e < 4; ++e) {
      const int row = (rgrp << 2) + e;
      float4 kf = kpre[e];
      bf16x4 kb4;
      kb4[0] = (__bf16)kf.x; kb4[1] = (__bf16)kf.y;
      kb4[2] = (__bf16)kf.z; kb4[3] = (__bf16)kf.w;
      *(bf16x4*)(ksh + row * KPITCH + (cb << 1)) = kb4;
    }
#pragma unroll
    for (int j = 0; j < 4; ++j) {
      bf16x4 vb4;
      vb4[0] = (__bf16)vpre[0][j]; vb4[1] = (__bf16)vpre[1][j];
      vb4[2] = (__bf16)vpre[2][j]; vb4[3] = (__bf16)vpre[3][j];
      *(bf16x4*)(vsh + (cb + j) * KPITCH + (rgrp << 3)) = vb4;
    }
    float4 pc[4], bc[4]; uint4 mc[4];
#pragma unroll
    for (int kf = 0; kf < 4; ++kf) { pc[kf] = ppre[kf]; bc[kf] = bpre[kf]; mc[kf] = mpre[kf]; }
    if (tt + 1 < Tq) { issueKV(kv0 + KB); issuePB(kv0 + KB); }
    barw();

    f32x4 s[4];
#pragma unroll
    for (int kf = 0; kf < 4; ++kf) { f32x4 z = {0.f, 0.f, 0.f, 0.f}; s[kf] = z; }
#pragma unroll
    for (int ks = 0; ks < 2; ++ks) {
#pragma unroll
      for (int kf = 0; kf < 4; ++kf) {
        const int kvr = kf * 16 + llo;
        bf16x8 ak = *(const bf16x8*)(ksh + kvr * KPITCH + ((ks * 32 + lhi * 8) << 1));
        s[kf] = __builtin_amdgcn_mfma_f32_16x16x32_bf16(ak, aq[ks], s[kf], 0, 0, 0);
      }
    }

    float p[4][4];
    float pmax = -FLT_MAX;
#pragma unroll
    for (int kf = 0; kf < 4; ++kf) {
      float pa[4] = {pc[kf].x, pc[kf].y, pc[kf].z, pc[kf].w};
      float ba[4] = {bc[kf].x, bc[kf].y, bc[kf].z, bc[kf].w};
      unsigned mb[4];
      if (mask4) { mb[0] = mc[kf].x; mb[1] = mc[kf].y; mb[2] = mc[kf].z; mb[3] = mc[kf].w; }
      else {
        mb[0] = mc[kf].x & 0xffu; mb[1] = (mc[kf].x >> 8) & 0xffu;
        mb[2] = (mc[kf].x >> 16) & 0xffu; mb[3] = mc[kf].x >> 24;
      }
#pragma unroll
      for (int r = 0; r < 4; ++r) {
        const int j = kv0 + kf * 16 + lhi * 4 + r;
        float sv = s[kf][r] + pa[r] + ba[r];
        if (j > qrow_g || mb[r] == 0u) sv = -FLT_MAX;
        p[kf][r] = sv;
        pmax = fmaxf(pmax, sv);
      }
    }
    pmax = fmaxf(pmax, __shfl_xor(pmax, 16));
    pmax = fmaxf(pmax, __shfl_xor(pmax, 32));
    const float mnew = fmaxf(m_r, pmax);
    const float resc = __expf(m_r - mnew);
    float psum = 0.f;
#pragma unroll
    for (int kf = 0; kf < 4; ++kf)
#pragma unroll
      for (int r = 0; r < 4; ++r) {
        float e = __expf(p[kf][r] - mnew);
        p[kf][r] = e;
        psum += e;
      }
    psum += __shfl_xor(psum, 16);
    psum += __shfl_xor(psum, 32);
    l_r = l_r * resc + psum;
    m_r = mnew;
#pragma unroll
    for (int df = 0; df < 4; ++df) {
      oacc[df][0] *= resc; oacc[df][1] *= resc;
      oacc[df][2] *= resc; oacc[df][3] *= resc;
    }

    unsigned U[4][2];
#pragma unroll
    for (int kf = 0; kf < 4; ++kf) {
      U[kf][0] = pack2(p[kf][0], p[kf][1]);
      U[kf][1] = pack2(p[kf][2], p[kf][3]);
    }
#pragma unroll
    for (int ks = 0; ks < 2; ++ks) {
      unsigned bb[4];
#pragma unroll
      for (int m = 0; m < 4; ++m) {
        const int src = llo + ((((lhi & 1) << 1) + (m >> 1)) << 4);
        const int va = __shfl((int)U[2 * ks + 0][m & 1], src);
        const int vb = __shfl((int)U[2 * ks + 1][m & 1], src);
        bb[m] = (lhi >> 1) ? (unsigned)vb : (unsigned)va;
      }
      union { unsigned u[4]; bf16x8 v; } pb_;
      pb_.u[0] = bb[0]; pb_.u[1] = bb[1]; pb_.u[2] = bb[2]; pb_.u[3] = bb[3];
#pragma unroll
      for (int df = 0; df < 4; ++df) {
        const int dr = df * 16 + llo;
        bf16x8 vf = *(const bf16x8*)(vsh + dr * KPITCH + ((ks * 32 + lhi * 8) << 1));
        oacc[df] = __builtin_amdgcn_mfma_f32_16x16x32_bf16(vf, pb_.v, oacc[df], 0, 0, 0);
      }
    }
    barw();
  }

  const int anyNeed = __syncthreads_or(m_r == -FLT_MAX);
  if (anyNeed) {
    if (t < DDIM) vmean_s[t] = 0.f;
    __syncthreads();
    {
      const int d = t & 63, part = t >> 6;
      float sacc = 0.f;
      for (int j = part; j < NN; j += 4) sacc += vg[((size_t)(h * NN + j)) * DDIM + d];
      atomicAdd(&vmean_s[d], sacc);
    }
    __syncthreads();
    if (t < DDIM) vmean_s[t] *= (1.0f / (float)NN);
    __syncthreads();
  }
  const float invl = 1.0f / l_r;
  const bool dead = (m_r == -FLT_MAX);
#pragma unroll
  for (int df = 0; df < 4; ++df) {
    const int dbase = df * 16 + lhi * 4;
    float4 o;
    o.x = dead ? vmean_s[dbase + 0] : oacc[df][0] * invl;
    o.y = dead ? vmean_s[dbase + 1] : oacc[df][1] * invl;
    o.z = dead ? vmean_s[dbase + 2] : oacc[df][2] * invl;
    o.w = dead ? vmean_s[dbase + 3] : oacc[df][3] * invl;
    *(float4*)(outg + ((size_t)(h * NN) + qrow_g) * DDIM + dbase) = o;
  }
}

extern "C" void kernel_launch(void* const* d_in, const int* in_sizes, int n_in,
                              void* d_out, int out_size, void* d_ws, size_t ws_size,
                              hipStream_t stream) {
  (void)in_sizes; (void)n_in; (void)out_size;
  const float* q    = (const float*)d_in[0];
  const float* k    = (const float*)d_in[1];
  const float* v    = (const float*)d_in[2];
  const unsigned int* mask = (const unsigned int*)d_in[3];
  const float* bias = (const float*)d_in[4];
  const float* prev = (const float*)d_in[5];
  float* out = (float*)d_out;

  if (ws_size >= WS_NEED) {
    float* wsf = (float*)d_ws;
    unsigned int* counter = (unsigned int*)wsf;          // [0]
    float* wsv   = wsf + 512;                            // vmean: 16*64 floats
    float* opart = wsf + WS_PART_OFF;                    // partials
    hipMemsetAsync(counter, 0, 4, stream);
    vmean_kernel<<<dim3(HH), 256, 0, stream>>>(v, wsv);
    attend_part<<<dim3(512), 512, 0, stream>>>(q, k, v, mask, bias, prev, opart, counter);
    attend_combine<<<dim3(16, HH), 256, 0, stream>>>(opart, wsv, out);
  } else {
    attend_single<<<dim3(32, HH), 256, 0, stream>>>(q, k, v, mask, bias, prev, out);
  }
}

// Round 12
// 171.158 us; speedup vs baseline: 1.0001x; 1.0001x over previous
//
#include <hip/hip_runtime.h>
#include <hip/hip_bf16.h>
#include <float.h>

#define NN 2048
#define HH 16
#define DDIM 64
#define QB 64   // q-rows per block = 4 waves x 16 rows
#define KB 64
#define KPITCH 144            // LDS row pitch in bytes (16B-aligned, bank-spread)
#define PARTF 4224            // floats per partial: 64x64 O + 64 m + 64 l
#define NSLOT 8               // max kv-chunk partials per q-tile (32 tiles / 4)
#define NCHUNK 2304           // 16 heads * 144 chunks
#define WS_PART_OFF 2048      // floats offset: [0]=counter, [512..1536) vmean
#define WS_NEED ((WS_PART_OFF + 32ull * HH * NSLOT * PARTF) * 4ull)

typedef __bf16 bf16x8 __attribute__((ext_vector_type(8)));
typedef __bf16 bf16x4 __attribute__((ext_vector_type(4)));
typedef float f32x4 __attribute__((ext_vector_type(4)));

// Raw barrier: LDS-writes visible; outstanding GLOBAL prefetch loads stay in flight.
__device__ __forceinline__ void barw() {
  __builtin_amdgcn_sched_barrier(0);
  asm volatile("s_waitcnt lgkmcnt(0)" ::: "memory");
  __builtin_amdgcn_s_barrier();
  __builtin_amdgcn_sched_barrier(0);
}

__device__ __forceinline__ unsigned pack2(float a, float b) {
  union { __bf16 h[2]; unsigned u; } x;
  x.h[0] = (__bf16)a; x.h[1] = (__bf16)b;
  return x.u;
}

// ============================================================================
// vmean: per-head V column means + counter reset (saves a memset launch).
// ============================================================================
__global__ __launch_bounds__(256) void vmean_kernel(
    const float* __restrict__ vg, float* __restrict__ wsv,
    unsigned int* __restrict__ counter)
{
  __shared__ float red[4][DDIM];
  const int h = blockIdx.x;
  const int t = threadIdx.x;
  if (h == 0 && t == 0) *counter = 0u;
  const int d = t & 63;
  const int part = t >> 6;        // 0..3, each covers 512 rows
  float s = 0.f;
  const float* vp = vg + ((size_t)(h * NN) + part * 512) * DDIM + d;
  for (int j = 0; j < 512; ++j) s += vp[(size_t)j * DDIM];
  red[part][d] = s;
  __syncthreads();
  if (t < DDIM) {
    wsv[h * DDIM + t] =
      (red[0][t] + red[1][t] + red[2][t] + red[3][t]) * (1.0f / (float)NN);
  }
}

// ============================================================================
// R12 part: R10 structure + DEPTH-2 prev/bias/mask register prefetch (A/B
// buffer sets, macro-duplicated tile body for static reg indexing). Each wave
// holds 24 outstanding PB loads (~2 tile periods of latency cover); VGPR ~165
// -> 3 waves/SIMD hardware occupancy -> 3 blocks/CU; grid 768 persistent.
// In-flight PB per CU: 192 KB -> ~288 KB (Little's-law attack on the HBM
// stream). KV stays depth-1 (L2-resident).
// ============================================================================
#define TILE_STEP(TT, PP, BB, MM, REISSUE)                                     \
  do {                                                                         \
    const int kv0_ = (TT) * KB;                                                \
    /* phase 1: stage K [kv][d] and V^T [d][kv], f32->bf16, pitch-144 */       \
    _Pragma("unroll")                                                          \
    for (int e = 0; e < 4; ++e) {                                              \
      const int row_ = (rgrp << 2) + e;                                        \
      float4 kf_ = kpre[e];                                                    \
      bf16x4 kb4_;                                                             \
      kb4_[0] = (__bf16)kf_.x; kb4_[1] = (__bf16)kf_.y;                        \
      kb4_[2] = (__bf16)kf_.z; kb4_[3] = (__bf16)kf_.w;                        \
      *(bf16x4*)(ksh + row_ * KPITCH + (cb << 1)) = kb4_;                      \
    }                                                                          \
    _Pragma("unroll")                                                          \
    for (int j = 0; j < 4; ++j) {                                              \
      bf16x4 vb4_;                                                             \
      vb4_[0] = (__bf16)vpre[0][j]; vb4_[1] = (__bf16)vpre[1][j];              \
      vb4_[2] = (__bf16)vpre[2][j]; vb4_[3] = (__bf16)vpre[3][j];              \
      *(bf16x4*)(vsh + (cb + j) * KPITCH + (rgrp << 3)) = vb4_;                \
    }                                                                          \
    if ((TT) + 1 < hi) issueKV(kv0_ + KB);                                     \
    barw();                                                                    \
    /* QK^T swapped: S^T[kv][q] */                                             \
    f32x4 s_[4];                                                               \
    _Pragma("unroll")                                                          \
    for (int kf = 0; kf < 4; ++kf) { f32x4 z_ = {0.f,0.f,0.f,0.f}; s_[kf] = z_; } \
    _Pragma("unroll")                                                          \
    for (int ks = 0; ks < 2; ++ks) {                                           \
      _Pragma("unroll")                                                        \
      for (int kf = 0; kf < 4; ++kf) {                                         \
        const int kvr_ = kf * 16 + llo;                                        \
        bf16x8 ak_ = *(const bf16x8*)(ksh + kvr_ * KPITCH + ((ks * 32 + lhi * 8) << 1)); \
        s_[kf] = __builtin_amdgcn_mfma_f32_16x16x32_bf16(ak_, aq[ks], s_[kf], 0, 0, 0); \
      }                                                                        \
    }                                                                          \
    /* softmax (consumes PP/BB/MM) */                                          \
    float p_[4][4];                                                            \
    float pmax_ = -FLT_MAX;                                                    \
    _Pragma("unroll")                                                          \
    for (int kf = 0; kf < 4; ++kf) {                                           \
      float pa_[4] = {PP[kf].x, PP[kf].y, PP[kf].z, PP[kf].w};                 \
      float ba_[4] = {BB[kf].x, BB[kf].y, BB[kf].z, BB[kf].w};                 \
      unsigned mb_[4];                                                         \
      if (mask4) { mb_[0] = MM[kf].x; mb_[1] = MM[kf].y; mb_[2] = MM[kf].z; mb_[3] = MM[kf].w; } \
      else {                                                                   \
        mb_[0] = MM[kf].x & 0xffu; mb_[1] = (MM[kf].x >> 8) & 0xffu;           \
        mb_[2] = (MM[kf].x >> 16) & 0xffu; mb_[3] = MM[kf].x >> 24;            \
      }                                                                        \
      _Pragma("unroll")                                                        \
      for (int r = 0; r < 4; ++r) {                                            \
        const int j_ = kv0_ + kf * 16 + lhi * 4 + r;                           \
        float sv_ = s_[kf][r] + pa_[r] + ba_[r];                               \
        if (j_ > qrow_g || mb_[r] == 0u) sv_ = -FLT_MAX;                       \
        p_[kf][r] = sv_;                                                       \
        pmax_ = fmaxf(pmax_, sv_);                                             \
      }                                                                        \
    }                                                                          \
    REISSUE;  /* PP/BB/MM fully consumed -> refill this buffer (flies 2 tiles) */ \
    pmax_ = fmaxf(pmax_, __shfl_xor(pmax_, 16));                               \
    pmax_ = fmaxf(pmax_, __shfl_xor(pmax_, 32));                               \
    const float mnew_ = fmaxf(m_r, pmax_);                                     \
    const float resc_ = __expf(m_r - mnew_);                                   \
    float psum_ = 0.f;                                                         \
    _Pragma("unroll")                                                          \
    for (int kf = 0; kf < 4; ++kf)                                             \
      _Pragma("unroll")                                                        \
      for (int r = 0; r < 4; ++r) {                                            \
        float e_ = __expf(p_[kf][r] - mnew_);                                  \
        p_[kf][r] = e_;                                                        \
        psum_ += e_;                                                           \
      }                                                                        \
    psum_ += __shfl_xor(psum_, 16);                                            \
    psum_ += __shfl_xor(psum_, 32);                                            \
    l_r = l_r * resc_ + psum_;                                                 \
    m_r = mnew_;                                                               \
    _Pragma("unroll")                                                          \
    for (int df = 0; df < 4; ++df) {                                           \
      oacc[df][0] *= resc_; oacc[df][1] *= resc_;                              \
      oacc[df][2] *= resc_; oacc[df][3] *= resc_;                              \
    }                                                                          \
    /* pack P; redistribute P^T into PV B-operand; PV MFMAs */                 \
    unsigned U_[4][2];                                                         \
    _Pragma("unroll")                                                          \
    for (int kf = 0; kf < 4; ++kf) {                                           \
      U_[kf][0] = pack2(p_[kf][0], p_[kf][1]);                                 \
      U_[kf][1] = pack2(p_[kf][2], p_[kf][3]);                                 \
    }                                                                          \
    _Pragma("unroll")                                                          \
    for (int ks = 0; ks < 2; ++ks) {                                           \
      unsigned bb2_[4];                                                        \
      _Pragma("unroll")                                                        \
      for (int m = 0; m < 4; ++m) {                                            \
        const int src_ = llo + ((((lhi & 1) << 1) + (m >> 1)) << 4);           \
        const int va_ = __shfl((int)U_[2 * ks + 0][m & 1], src_);              \
        const int vb_ = __shfl((int)U_[2 * ks + 1][m & 1], src_);              \
        bb2_[m] = (lhi >> 1) ? (unsigned)vb_ : (unsigned)va_;                  \
      }                                                                        \
      union { unsigned u[4]; bf16x8 v; } pbu_;                                 \
      pbu_.u[0] = bb2_[0]; pbu_.u[1] = bb2_[1]; pbu_.u[2] = bb2_[2]; pbu_.u[3] = bb2_[3]; \
      _Pragma("unroll")                                                        \
      for (int df = 0; df < 4; ++df) {                                         \
        const int dr_ = df * 16 + llo;                                         \
        bf16x8 vf_ = *(const bf16x8*)(vsh + dr_ * KPITCH + ((ks * 32 + lhi * 8) << 1)); \
        oacc[df] = __builtin_amdgcn_mfma_f32_16x16x32_bf16(vf_, pbu_.v, oacc[df], 0, 0, 0); \
      }                                                                        \
    }                                                                          \
    barw();                                                                    \
  } while (0)

__global__ __launch_bounds__(256, 2) void attend_part(
    const float* __restrict__ qg, const float* __restrict__ kg,
    const float* __restrict__ vg, const unsigned int* __restrict__ maskw,
    const float* __restrict__ biasg, const float* __restrict__ prevg,
    float* __restrict__ opart, unsigned int* __restrict__ counter)
{
  __shared__ char ksh[KB * KPITCH]   __attribute__((aligned(16))); // [kv][d] bf16
  __shared__ char vsh[DDIM * KPITCH] __attribute__((aligned(16))); // [d][kv] bf16
  __shared__ int chunk_s;

  const int t    = threadIdx.x;
  const int lane = t & 63;
  const int w    = t >> 6;

  // --- mask element-width detection: 4-byte (int/float bool) vs 1-byte ---
  unsigned int mwrd = maskw[t & 255];
  const int mask4 = __syncthreads_and(mwrd == 0u || mwrd == 1u || mwrd == 0x3F800000u);

  const int llo = lane & 15;
  const int lhi = lane >> 4;
  const int cbi  = t & 15;        // staging col group: cb = cbi*4
  const int cb   = cbi << 2;
  const int rgrp = t >> 4;        // staging row group: rows rgrp*4 .. +3

  for (;;) {
    if (t == 0) chunk_s = (int)atomicAdd(counter, 1u);
    __syncthreads();
    const int c = chunk_s;
    if (c >= NCHUNK) break;
    const int h    = c & 15;
    const int rank = c >> 4;

    int qt, ci, len;
    if (rank < 120) {
      int kk = rank;
      qt = 31;
      for (;;) {
        const int nf = (qt + 1) >> 2;
        if (kk < nf) { ci = kk; len = 4; break; }
        kk -= nf; --qt;
      }
    } else {
      const int idx = rank - 120;
      const int s = 3 - (idx >> 3);
      const int j = idx & 7;
      qt  = (j << 2) + s - 1;
      ci  = j;
      len = s;
    }
    const int lo = ci << 2;
    const int hi = lo + len;
    const int qrow0 = qt * QB;
    const int qrow_g = qrow0 + w * 16 + llo;   // this lane's q-row

    // --- Q fragments (B operand), scale 1/8 folded in ---
    bf16x8 aq[2];
    {
      const float* qp = qg + ((size_t)(h * NN + qrow_g)) * DDIM + lhi * 8;
#pragma unroll
      for (int ks = 0; ks < 2; ++ks) {
        float4 f0 = *(const float4*)(qp + ks * 32);
        float4 f1 = *(const float4*)(qp + ks * 32 + 4);
        bf16x8 a;
        a[0] = (__bf16)(f0.x * 0.125f); a[1] = (__bf16)(f0.y * 0.125f);
        a[2] = (__bf16)(f0.z * 0.125f); a[3] = (__bf16)(f0.w * 0.125f);
        a[4] = (__bf16)(f1.x * 0.125f); a[5] = (__bf16)(f1.y * 0.125f);
        a[6] = (__bf16)(f1.z * 0.125f); a[7] = (__bf16)(f1.w * 0.125f);
        aq[ks] = a;
      }
    }

    f32x4 oacc[4];   // O^T frags: oacc[df][r] = O[q=llo-row][d=df*16+lhi*4+r]
#pragma unroll
    for (int i = 0; i < 4; ++i) { f32x4 z = {0.f, 0.f, 0.f, 0.f}; oacc[i] = z; }
    float m_r = -FLT_MAX, l_r = 0.f;

    // ---- prefetch registers ----
    float4 kpre[4], vpre[4];
    float4 ppreA[4], bpreA[4]; uint4 mpreA[4];   // PB buffer A
    float4 ppreB[4], bpreB[4]; uint4 mpreB[4];   // PB buffer B

    auto issueKV = [&](int kv0) {
#pragma unroll
      for (int e = 0; e < 4; ++e) {
        const int row = (rgrp << 2) + e;
        const size_t gofs = ((size_t)(h * NN + kv0 + row)) * DDIM + cb;
        kpre[e] = *(const float4*)(kg + gofs);
        vpre[e] = *(const float4*)(vg + gofs);
      }
    };
    auto issuePB_A = [&](int kv0) {
#pragma unroll
      for (int kf = 0; kf < 4; ++kf) {
        const int col = kv0 + kf * 16 + lhi * 4;
        const size_t base = ((size_t)(h * NN) + qrow_g) * NN + col;
        ppreA[kf] = *(const float4*)(prevg + base);
        bpreA[kf] = *(const float4*)(biasg + base);
        const size_t midx = (size_t)qrow_g * NN + col;
        if (mask4) mpreA[kf] = *(const uint4*)(maskw + midx);
        else       mpreA[kf].x = *(const unsigned int*)((const unsigned char*)maskw + midx);
      }
    };
    auto issuePB_B = [&](int kv0) {
#pragma unroll
      for (int kf = 0; kf < 4; ++kf) {
        const int col = kv0 + kf * 16 + lhi * 4;
        const size_t base = ((size_t)(h * NN) + qrow_g) * NN + col;
        ppreB[kf] = *(const float4*)(prevg + base);
        bpreB[kf] = *(const float4*)(biasg + base);
        const size_t midx = (size_t)qrow_g * NN + col;
        if (mask4) mpreB[kf] = *(const uint4*)(maskw + midx);
        else       mpreB[kf].x = *(const unsigned int*)((const unsigned char*)maskw + midx);
      }
    };

    issueKV(lo * KB);
    issuePB_A(lo * KB);
    if (lo + 1 < hi) issuePB_B((lo + 1) * KB);

    for (int tt = lo; tt < hi; tt += 2) {
      TILE_STEP(tt, ppreA, bpreA, mpreA,
                { if (tt + 2 < hi) issuePB_A((tt + 2) * KB); });
      if (tt + 1 < hi) {
        TILE_STEP(tt + 1, ppreB, bpreB, mpreB,
                  { if (tt + 3 < hi) issuePB_B((tt + 3) * KB); });
      }
    }

    // ---- write partial (unnormalized O, m, l) ----
    float* pb = opart + (size_t)(((h * 32 + qt) << 3) + ci) * PARTF;
    const int rowl = w * 16 + llo;
#pragma unroll
    for (int df = 0; df < 4; ++df) {
      *(f32x4*)(pb + rowl * 64 + df * 16 + lhi * 4) = oacc[df];
    }
    if (lhi == 0) {
      pb[4096 + rowl] = m_r;
      pb[4160 + rowl] = l_r;
    }
    __syncthreads();   // chunk done; safe to reuse chunk_s/LDS
  } // chunk loop
}

// ============================================================================
// combine: merge up to 8 kv-chunk partials per (qt,h); dead rows -> vmean.
// ============================================================================
__global__ __launch_bounds__(256) void attend_combine(
    const float* __restrict__ opart, const float* __restrict__ wsv,
    float* __restrict__ outg)
{
  const int qt  = blockIdx.x;
  const int h   = blockIdx.y;
  const int t   = threadIdx.x;
  const int nch = (qt + 4) >> 2;   // ceil((qt+1)/4)
  const float* base = opart + (size_t)((h * 32 + qt) << 3) * PARTF;
  const int r  = t >> 2;          // 0..63
  const int c0 = (t & 3) * 16;    // 0,16,32,48

  float m = -FLT_MAX;
  for (int ci = 0; ci < nch; ++ci)
    m = fmaxf(m, base[(size_t)ci * PARTF + 4096 + r]);
  const bool dead = (m == -FLT_MAX);

  float l = 0.f;
  f32x4 a0 = {0,0,0,0}, a1 = {0,0,0,0}, a2 = {0,0,0,0}, a3 = {0,0,0,0};
  for (int ci = 0; ci < nch; ++ci) {
    const float* pb = base + (size_t)ci * PARTF;
    const float wgt = dead ? 0.f : __expf(pb[4096 + r] - m);
    l += pb[4160 + r] * wgt;
    const f32x4 b0 = *(const f32x4*)(pb + r * 64 + c0 + 0);
    const f32x4 b1 = *(const f32x4*)(pb + r * 64 + c0 + 4);
    const f32x4 b2 = *(const f32x4*)(pb + r * 64 + c0 + 8);
    const f32x4 b3 = *(const f32x4*)(pb + r * 64 + c0 + 12);
    a0 += b0 * wgt; a1 += b1 * wgt; a2 += b2 * wgt; a3 += b3 * wgt;
  }

  const float invl = dead ? 0.f : (1.0f / l);
  float* op = outg + ((size_t)(h * NN) + qt * QB + r) * DDIM + c0;
  const float* vm = wsv + h * DDIM + c0;
#pragma unroll
  for (int i = 0; i < 4; ++i) {
    const f32x4 ai = (i == 0) ? a0 : (i == 1) ? a1 : (i == 2) ? a2 : a3;
    float4 o;
    o.x = dead ? vm[i * 4 + 0] : ai[0] * invl;
    o.y = dead ? vm[i * 4 + 1] : ai[1] * invl;
    o.z = dead ? vm[i * 4 + 2] : ai[2] * invl;
    o.w = dead ? vm[i * 4 + 3] : ai[3] * invl;
    *(float4*)(op + i * 4) = o;
  }
}

// ============================================================================
// Fallback: single-kernel version (used only if ws_size is too small).
// ============================================================================
__global__ __launch_bounds__(256, 2) void attend_single(
    const float* __restrict__ qg, const float* __restrict__ kg,
    const float* __restrict__ vg, const unsigned int* __restrict__ maskw,
    const float* __restrict__ biasg, const float* __restrict__ prevg,
    float* __restrict__ outg)
{
  __shared__ char  ksh[KB * KPITCH]   __attribute__((aligned(16)));
  __shared__ char  vsh[DDIM * KPITCH] __attribute__((aligned(16)));
  __shared__ float vmean_s[DDIM];

  const int t    = threadIdx.x;
  const int lane = t & 63;
  const int w    = t >> 6;
  const int x    = blockIdx.x;
  const int h    = blockIdx.y;
  const int qt   = (h < 8) ? x : (31 - x);
  const int qrow0 = qt * QB;

  unsigned int mwrd = maskw[t & 255];
  const int mask4 = __syncthreads_and(mwrd == 0u || mwrd == 1u || mwrd == 0x3F800000u);

  const int llo = lane & 15;
  const int lhi = lane >> 4;
  const int cbi  = t & 15;
  const int cb   = cbi << 2;
  const int rgrp = t >> 4;
  const int qrow_g = qrow0 + w * 16 + llo;

  bf16x8 aq[2];
  {
    const float* qp = qg + ((size_t)(h * NN + qrow_g)) * DDIM + lhi * 8;
#pragma unroll
    for (int ks = 0; ks < 2; ++ks) {
      float4 f0 = *(const float4*)(qp + ks * 32);
      float4 f1 = *(const float4*)(qp + ks * 32 + 4);
      bf16x8 a;
      a[0] = (__bf16)(f0.x * 0.125f); a[1] = (__bf16)(f0.y * 0.125f);
      a[2] = (__bf16)(f0.z * 0.125f); a[3] = (__bf16)(f0.w * 0.125f);
      a[4] = (__bf16)(f1.x * 0.125f); a[5] = (__bf16)(f1.y * 0.125f);
      a[6] = (__bf16)(f1.z * 0.125f); a[7] = (__bf16)(f1.w * 0.125f);
      aq[ks] = a;
    }
  }

  f32x4 oacc[4];
#pragma unroll
  for (int i = 0; i < 4; ++i) { f32x4 z = {0.f, 0.f, 0.f, 0.f}; oacc[i] = z; }
  float m_r = -FLT_MAX, l_r = 0.f;

  float4 kpre[4], vpre[4];
  float4 ppre[4], bpre[4];
  uint4  mpre[4];

  auto issueKV = [&](int kv0) {
#pragma unroll
    for (int e = 0; e < 4; ++e) {
      const int row = (rgrp << 2) + e;
      const size_t gofs = ((size_t)(h * NN + kv0 + row)) * DDIM + cb;
      kpre[e] = *(const float4*)(kg + gofs);
      vpre[e] = *(const float4*)(vg + gofs);
    }
  };
  auto issuePB = [&](int kv0) {
#pragma unroll
    for (int kf = 0; kf < 4; ++kf) {
      const int col = kv0 + kf * 16 + lhi * 4;
      const size_t base = ((size_t)(h * NN) + qrow_g) * NN + col;
      ppre[kf] = *(const float4*)(prevg + base);
      bpre[kf] = *(const float4*)(biasg + base);
      const size_t midx = (size_t)qrow_g * NN + col;
      if (mask4) mpre[kf] = *(const uint4*)(maskw + midx);
      else       mpre[kf].x = *(const unsigned int*)((const unsigned char*)maskw + midx);
    }
  };

  const int Tq = qt + 1;
  issueKV(0);
  issuePB(0);

  for (int tt = 0; tt < Tq; ++tt) {
    const int kv0 = tt * KB;
#pragma unroll
    for (int e = 0; e < 4; ++e) {
      const int row = (rgrp << 2) + e;
      float4 kf = kpre[e];
      bf16x4 kb4;
      kb4[0] = (__bf16)kf.x; kb4[1] = (__bf16)kf.y;
      kb4[2] = (__bf16)kf.z; kb4[3] = (__bf16)kf.w;
      *(bf16x4*)(ksh + row * KPITCH + (cb << 1)) = kb4;
    }
#pragma unroll
    for (int j = 0; j < 4; ++j) {
      bf16x4 vb4;
      vb4[0] = (__bf16)vpre[0][j]; vb4[1] = (__bf16)vpre[1][j];
      vb4[2] = (__bf16)vpre[2][j]; vb4[3] = (__bf16)vpre[3][j];
      *(bf16x4*)(vsh + (cb + j) * KPITCH + (rgrp << 3)) = vb4;
    }
    float4 pc[4], bc[4]; uint4 mc[4];
#pragma unroll
    for (int kf = 0; kf < 4; ++kf) { pc[kf] = ppre[kf]; bc[kf] = bpre[kf]; mc[kf] = mpre[kf]; }
    if (tt + 1 < Tq) { issueKV(kv0 + KB); issuePB(kv0 + KB); }
    barw();

    f32x4 s[4];
#pragma unroll
    for (int kf = 0; kf < 4; ++kf) { f32x4 z = {0.f, 0.f, 0.f, 0.f}; s[kf] = z; }
#pragma unroll
    for (int ks = 0; ks < 2; ++ks) {
#pragma unroll
      for (int kf = 0; kf < 4; ++kf) {
        const int kvr = kf * 16 + llo;
        bf16x8 ak = *(const bf16x8*)(ksh + kvr * KPITCH + ((ks * 32 + lhi * 8) << 1));
        s[kf] = __builtin_amdgcn_mfma_f32_16x16x32_bf16(ak, aq[ks], s[kf], 0, 0, 0);
      }
    }

    float p[4][4];
    float pmax = -FLT_MAX;
#pragma unroll
    for (int kf = 0; kf < 4; ++kf) {
      float pa[4] = {pc[kf].x, pc[kf].y, pc[kf].z, pc[kf].w};
      float ba[4] = {bc[kf].x, bc[kf].y, bc[kf].z, bc[kf].w};
      unsigned mb[4];
      if (mask4) { mb[0] = mc[kf].x; mb[1] = mc[kf].y; mb[2] = mc[kf].z; mb[3] = mc[kf].w; }
      else {
        mb[0] = mc[kf].x & 0xffu; mb[1] = (mc[kf].x >> 8) & 0xffu;
        mb[2] = (mc[kf].x >> 16) & 0xffu; mb[3] = mc[kf].x >> 24;
      }
#pragma unroll
      for (int r = 0; r < 4; ++r) {
        const int j = kv0 + kf * 16 + lhi * 4 + r;
        float sv = s[kf][r] + pa[r] + ba[r];
        if (j > qrow_g || mb[r] == 0u) sv = -FLT_MAX;
        p[kf][r] = sv;
        pmax = fmaxf(pmax, sv);
      }
    }
    pmax = fmaxf(pmax, __shfl_xor(pmax, 16));
    pmax = fmaxf(pmax, __shfl_xor(pmax, 32));
    const float mnew = fmaxf(m_r, pmax);
    const float resc = __expf(m_r - mnew);
    float psum = 0.f;
#pragma unroll
    for (int kf = 0; kf < 4; ++kf)
#pragma unroll
      for (int r = 0; r < 4; ++r) {
        float e = __expf(p[kf][r] - mnew);
        p[kf][r] = e;
        psum += e;
      }
    psum += __shfl_xor(psum, 16);
    psum += __shfl_xor(psum, 32);
    l_r = l_r * resc + psum;
    m_r = mnew;
#pragma unroll
    for (int df = 0; df < 4; ++df) {
      oacc[df][0] *= resc; oacc[df][1] *= resc;
      oacc[df][2] *= resc; oacc[df][3] *= resc;
    }

    unsigned U[4][2];
#pragma unroll
    for (int kf = 0; kf < 4; ++kf) {
      U[kf][0] = pack2(p[kf][0], p[kf][1]);
      U[kf][1] = pack2(p[kf][2], p[kf][3]);
    }
#pragma unroll
    for (int ks = 0; ks < 2; ++ks) {
      unsigned bb[4];
#pragma unroll
      for (int m = 0; m < 4; ++m) {
        const int src = llo + ((((lhi & 1) << 1) + (m >> 1)) << 4);
        const int va = __shfl((int)U[2 * ks + 0][m & 1], src);
        const int vb = __shfl((int)U[2 * ks + 1][m & 1], src);
        bb[m] = (lhi >> 1) ? (unsigned)vb : (unsigned)va;
      }
      union { unsigned u[4]; bf16x8 v; } pb_;
      pb_.u[0] = bb[0]; pb_.u[1] = bb[1]; pb_.u[2] = bb[2]; pb_.u[3] = bb[3];
#pragma unroll
      for (int df = 0; df < 4; ++df) {
        const int dr = df * 16 + llo;
        bf16x8 vf = *(const bf16x8*)(vsh + dr * KPITCH + ((ks * 32 + lhi * 8) << 1));
        oacc[df] = __builtin_amdgcn_mfma_f32_16x16x32_bf16(vf, pb_.v, oacc[df], 0, 0, 0);
      }
    }
    barw();
  }

  const int anyNeed = __syncthreads_or(m_r == -FLT_MAX);
  if (anyNeed) {
    if (t < DDIM) vmean_s[t] = 0.f;
    __syncthreads();
    {
      const int d = t & 63, part = t >> 6;
      float sacc = 0.f;
      for (int j = part; j < NN; j += 4) sacc += vg[((size_t)(h * NN + j)) * DDIM + d];
      atomicAdd(&vmean_s[d], sacc);
    }
    __syncthreads();
    if (t < DDIM) vmean_s[t] *= (1.0f / (float)NN);
    __syncthreads();
  }
  const float invl = 1.0f / l_r;
  const bool dead = (m_r == -FLT_MAX);
#pragma unroll
  for (int df = 0; df < 4; ++df) {
    const int dbase = df * 16 + lhi * 4;
    float4 o;
    o.x = dead ? vmean_s[dbase + 0] : oacc[df][0] * invl;
    o.y = dead ? vmean_s[dbase + 1] : oacc[df][1] * invl;
    o.z = dead ? vmean_s[dbase + 2] : oacc[df][2] * invl;
    o.w = dead ? vmean_s[dbase + 3] : oacc[df][3] * invl;
    *(float4*)(outg + ((size_t)(h * NN) + qrow_g) * DDIM + dbase) = o;
  }
}

extern "C" void kernel_launch(void* const* d_in, const int* in_sizes, int n_in,
                              void* d_out, int out_size, void* d_ws, size_t ws_size,
                              hipStream_t stream) {
  (void)in_sizes; (void)n_in; (void)out_size;
  const float* q    = (const float*)d_in[0];
  const float* k    = (const float*)d_in[1];
  const float* v    = (const float*)d_in[2];
  const unsigned int* mask = (const unsigned int*)d_in[3];
  const float* bias = (const float*)d_in[4];
  const float* prev = (const float*)d_in[5];
  float* out = (float*)d_out;

  if (ws_size >= WS_NEED) {
    float* wsf = (float*)d_ws;
    unsigned int* counter = (unsigned int*)wsf;          // [0]
    float* wsv   = wsf + 512;                            // vmean: 16*64 floats
    float* opart = wsf + WS_PART_OFF;                    // partials
    vmean_kernel<<<dim3(HH), 256, 0, stream>>>(v, wsv, counter);
    attend_part<<<dim3(768), 256, 0, stream>>>(q, k, v, mask, bias, prev, opart, counter);
    attend_combine<<<dim3(32, HH), 256, 0, stream>>>(opart, wsv, out);
  } else {
    attend_single<<<dim3(32, HH), 256, 0, stream>>>(q, k, v, mask, bias, prev, out);
  }
}